// Round 2
// baseline (747.233 us; speedup 1.0000x reference)
//
#include <hip/hip_runtime.h>
#include <hip/hip_bf16.h>
#include <hip/hip_fp16.h>

typedef _Float16 f16;
typedef _Float16 f16x8 __attribute__((ext_vector_type(8)));
typedef float f32x4 __attribute__((ext_vector_type(4)));

union U128 { uint4 u; f16x8 v; };
union H4 { ushort4 u; f16 h[4]; };

__device__ inline f16x8 ldg_f16x8(const f16* p) {
    U128 t;
    t.u = *reinterpret_cast<const uint4*>(p);
    return t.v;
}

// ---------------- W transpose + f32->f16 convert: Wt[n][k] = (f16) W[k][n] ----------------
__global__ void k_convert_wt(const float* __restrict__ W, f16* __restrict__ Wt, int K, int N) {
    int t = blockIdx.x * blockDim.x + threadIdx.x;
    if (t >= K * N) return;
    int k = t / N, n = t % N;                 // coalesced read of W
    Wt[(size_t)n * K + k] = (f16)W[t];        // scattered 2B writes, tiny matrix (L2)
}

// ---------------- gather-mean layer 1: means[row][512] = mean_k feats[nb[row][k]][:] -------
// one wave per output row; lane covers dims [lane*4..+3] and [256+lane*4..+3]
__global__ __launch_bounds__(256) void k_gather_mean1(const float* __restrict__ feats,
                                                      const int* __restrict__ nb,
                                                      f16* __restrict__ means) {
    const int row  = blockIdx.x * 4 + (threadIdx.x >> 6);
    const int lane = threadIdx.x & 63;
    const int base = row * 11;
    float4 a0 = {0.f, 0.f, 0.f, 0.f};
    float4 a1 = {0.f, 0.f, 0.f, 0.f};
#pragma unroll
    for (int k = 0; k < 11; ++k) {
        const int src = nb[base + k];
        const float4* p = reinterpret_cast<const float4*>(feats + (size_t)src * 512);
        float4 x = p[lane];
        float4 y = p[64 + lane];
        a0.x += x.x; a0.y += x.y; a0.z += x.z; a0.w += x.w;
        a1.x += y.x; a1.y += y.y; a1.z += y.z; a1.w += y.w;
    }
    const float s = 1.0f / 11.0f;
    H4 o0, o1;
    o0.h[0] = (f16)(a0.x * s); o0.h[1] = (f16)(a0.y * s);
    o0.h[2] = (f16)(a0.z * s); o0.h[3] = (f16)(a0.w * s);
    o1.h[0] = (f16)(a1.x * s); o1.h[1] = (f16)(a1.y * s);
    o1.h[2] = (f16)(a1.z * s); o1.h[3] = (f16)(a1.w * s);
    f16* dst = means + (size_t)row * 512;
    *reinterpret_cast<ushort4*>(dst + lane * 4)       = o0.u;
    *reinterpret_cast<ushort4*>(dst + 256 + lane * 4) = o1.u;
}

// ---------------- gather-mean layer 2: means[row][256] = mean_k h[nb[row][k]][:] -----------
__global__ __launch_bounds__(256) void k_gather_mean2(const f16* __restrict__ h,
                                                      const int* __restrict__ nb,
                                                      f16* __restrict__ means) {
    const int row  = blockIdx.x * 4 + (threadIdx.x >> 6);
    const int lane = threadIdx.x & 63;
    const int base = row * 11;
    float a[4] = {0.f, 0.f, 0.f, 0.f};
#pragma unroll
    for (int k = 0; k < 11; ++k) {
        const int src = nb[base + k];
        H4 t;
        t.u = *reinterpret_cast<const ushort4*>(h + (size_t)src * 256 + lane * 4);
        a[0] += (float)t.h[0]; a[1] += (float)t.h[1];
        a[2] += (float)t.h[2]; a[3] += (float)t.h[3];
    }
    const float s = 1.0f / 11.0f;
    H4 o;
#pragma unroll
    for (int j = 0; j < 4; ++j) o.h[j] = (f16)(a[j] * s);
    *reinterpret_cast<ushort4*>(means + (size_t)row * 256 + lane * 4) = o.u;
}

// ---------------- fused GEMM + relu + l2norm ----------------------------------------------
// C[64 rows][N cols] per block; 4 waves, wave w owns cols [w*N/4 .. +N/4), all 64 rows.
// A: [M][K] f16 row-major (means). Wt: [N][K] f16 (B^T). K%32==0, N%64==0 assumed.
// MFMA 16x16x32_f16 layouts: A lane holds A[l%16][8*(l/16)+b]; B lane holds B[8*(l/16)+b][l%16];
// D lane holds D[4*(l/16)+i][l%16]   (m89-verified mapping).
template<int K, int N, bool OUTF32>
__global__ __launch_bounds__(256) void k_gemm_fused(const f16* __restrict__ A,
                                                    const f16* __restrict__ Wt,
                                                    void* __restrict__ outp) {
    constexpr int CW = N / 4;    // cols per wave
    constexpr int F  = CW / 16;  // 16-col fragments per wave
    const int tid  = threadIdx.x;
    const int w    = tid >> 6;
    const int l    = tid & 63;
    const int lr   = l & 15;
    const int lq   = l >> 4;
    const size_t m0 = (size_t)blockIdx.x * 64;
    const int col0  = w * CW;

    f32x4 acc[4][F] = {};

    for (int ks = 0; ks < K / 32; ++ks) {
        const int kk = ks * 32 + lq * 8;
        f16x8 a[4], b[F];
#pragma unroll
        for (int g = 0; g < 4; ++g)
            a[g] = ldg_f16x8(A + (m0 + 16 * g + lr) * K + kk);
#pragma unroll
        for (int f = 0; f < F; ++f)
            b[f] = ldg_f16x8(Wt + (size_t)(col0 + 16 * f + lr) * K + kk);
#pragma unroll
        for (int g = 0; g < 4; ++g)
#pragma unroll
            for (int f = 0; f < F; ++f)
                acc[g][f] = __builtin_amdgcn_mfma_f32_16x16x32_f16(a[g], b[f], acc[g][f], 0, 0, 0);
    }

    // relu + per-row sum-of-squares partials (this wave's columns only)
    float p[4][4];
#pragma unroll
    for (int g = 0; g < 4; ++g)
#pragma unroll
        for (int i = 0; i < 4; ++i) {
            float s = 0.f;
#pragma unroll
            for (int f = 0; f < F; ++f) {
                float v = acc[g][f][i];
                v = v > 0.f ? v : 0.f;
                acc[g][f][i] = v;
                s += v * v;
            }
            p[g][i] = s;
        }
    // reduce across the 16 lanes holding the same row (xor masks stay within l/16 groups)
#pragma unroll
    for (int off = 1; off < 16; off <<= 1)
#pragma unroll
        for (int g = 0; g < 4; ++g)
#pragma unroll
            for (int i = 0; i < 4; ++i)
                p[g][i] += __shfl_xor(p[g][i], off);

    __shared__ float sums[4][64];
    if (lr == 0) {
#pragma unroll
        for (int g = 0; g < 4; ++g)
#pragma unroll
            for (int i = 0; i < 4; ++i)
                sums[w][16 * g + 4 * lq + i] = p[g][i];
    }
    __syncthreads();

#pragma unroll
    for (int g = 0; g < 4; ++g)
#pragma unroll
        for (int i = 0; i < 4; ++i) {
            const int r = 16 * g + 4 * lq + i;
            const float s   = sums[0][r] + sums[1][r] + sums[2][r] + sums[3][r];
            const float inv = 1.0f / fmaxf(sqrtf(s), 1e-12f);
#pragma unroll
            for (int f = 0; f < F; ++f) {
                const float v = acc[g][f][i] * inv;
                const size_t off = (m0 + r) * N + (size_t)(col0 + 16 * f + lr);
                if (OUTF32) ((float*)outp)[off] = v;
                else        ((f16*)outp)[off]   = (f16)v;
            }
        }
}

// ------------------------------------------------------------------------------------------
extern "C" void kernel_launch(void* const* d_in, const int* in_sizes, int n_in,
                              void* d_out, int out_size, void* d_ws, size_t ws_size,
                              hipStream_t stream) {
    const float* feats = (const float*)d_in[0];   // [262144, 512]
    const int*   nb1   = (const int*)d_in[1];     // [32768, 11]
    const int*   nb2   = (const int*)d_in[2];     // [4096, 11]
    const float* W1    = (const float*)d_in[3];   // [512, 256]
    const float* W2    = (const float*)d_in[4];   // [256, 128]
    float* out = (float*)d_out;                   // [4096, 128]

    // workspace layout (f16 elements): ~50.3 MB total
    f16* means1 = (f16*)d_ws;                          // 32768*512
    f16* h      = means1 + (size_t)32768 * 512;        // 32768*256
    f16* means2 = h      + (size_t)32768 * 256;        // 4096*256
    f16* wt1    = means2 + (size_t)4096 * 256;         // 256*512
    f16* wt2    = wt1    + (size_t)256 * 512;          // 128*256

    k_convert_wt<<<(512 * 256 + 255) / 256, 256, 0, stream>>>(W1, wt1, 512, 256);
    k_convert_wt<<<(256 * 128 + 255) / 256, 256, 0, stream>>>(W2, wt2, 256, 128);

    k_gather_mean1<<<32768 / 4, 256, 0, stream>>>(feats, nb1, means1);
    k_gemm_fused<512, 256, false><<<32768 / 64, 256, 0, stream>>>(means1, wt1, h);

    k_gather_mean2<<<4096 / 4, 256, 0, stream>>>(h, nb2, means2);
    k_gemm_fused<256, 128, true><<<4096 / 64, 256, 0, stream>>>(means2, wt2, out);
}